// Round 14
// baseline (817.592 us; speedup 1.0000x reference)
//
#include <hip/hip_runtime.h>
#include <math.h>
#include <stdint.h>

#define TOKENS 32768
#define DM 2048
#define DH 1024
#define NE 16
#define BM 128
#define BN 512
#define NPASS 2
#define BK 32
#define NSTAGE 64              // DM / BK
#define RT_TAU 5e-5f
#define FB_TAU 5e-4f
#define XSC 16.0f              // x pre-scale (2^4)
#define WSC 64.0f              // W pre-scale (2^6)
#define DESC (1.0f/1024.0f)    // acc descale (2^-10)

// output layout (floats): gates[T*2] | indices[T*2] | probs[T*16]
#define OFF_IDX  (TOKENS * 2)
#define OFF_PROB (TOKENS * 4)

// ws layout: [0] cnt | [1024] list (32768 int) | [132096] wimg (8 MB fp16 hi/lo image)
#define WS_LIST 1024
#define WS_WT   132096
#define WIMG_BYTES ((size_t)NSTAGE * NPASS * 65536)     // 8 MB
#define WS_NEEDED ((size_t)WS_WT + WIMG_BYTES)
#define RCAP 512

typedef _Float16 f16x8 __attribute__((ext_vector_type(8)));
typedef short    bf16x8 __attribute__((ext_vector_type(8)));
typedef float    f32x16 __attribute__((ext_vector_type(16)));

static __device__ __forceinline__ void gload_lds16(const void* g, void* l) {
    __builtin_amdgcn_global_load_lds(
        (const __attribute__((address_space(1))) void*)g,
        (__attribute__((address_space(3))) void*)l, 16, 0, 0);
}

// split 8 scaled floats into fp16 hi + residual lo
static __device__ __forceinline__ void cvt_split8(float4 u, float4 v, f16x8& hi, f16x8& lo) {
    float f[8] = {u.x * XSC, u.y * XSC, u.z * XSC, u.w * XSC,
                  v.x * XSC, v.y * XSC, v.z * XSC, v.w * XSC};
    #pragma unroll
    for (int j = 0; j < 8; ++j) {
        _Float16 h = (_Float16)f[j];
        hi[j] = h;
        lo[j] = (_Float16)(f[j] - (float)h);
    }
}

// ---------------- prep: W1 -> per-stage LDS byte image (64 KB each) ----------------
// image id = s*2+p (s in 0..63). Layout: [q 0..3][pl 0..1][n 0..511][8 fp16];
// byte = ((q*2+pl)*512 + n)*16; chunk q holds k = s*32 + q*8 .. +7.
__global__ __launch_bounds__(256)
void prep_w16(const float* __restrict__ W1, char* __restrict__ wimg) {
    const int bid = blockIdx.x;            // 0..127
    const int s = bid >> 1, p = bid & 1;
    char* img = wimg + ((size_t)bid << 16);
    const int tid = threadIdx.x;
    #pragma unroll
    for (int rep = 0; rep < 2; ++rep) {
        const int n = tid + rep * 256;
        #pragma unroll
        for (int q = 0; q < 4; ++q) {
            f16x8 hi, lo;
            #pragma unroll
            for (int j = 0; j < 8; ++j) {
                float ww = W1[(size_t)(s * 32 + q * 8 + j) * DH + p * 512 + n] * WSC;
                _Float16 h = (_Float16)ww;
                hi[j] = h;
                lo[j] = (_Float16)(ww - (float)h);
            }
            *(f16x8*)(img + ((q * 2 + 0) * 512 + n) * 16) = hi;
            *(f16x8*)(img + ((q * 2 + 1) * 512 + n) * 16) = lo;
        }
    }
}

// ---------------- fused GEMM1: 16 waves, 64x64 wave tile, acc=64 -> 4 waves/SIMD ----------------
__global__ __launch_bounds__(1024, 1)
void router16(const float* __restrict__ x, const char* __restrict__ wimg,
              const float* __restrict__ b1, const float* __restrict__ W2,
              const float* __restrict__ b2, float* __restrict__ out,
              int* __restrict__ cnt, int* __restrict__ list)
{
    // 160 KB exactly: B dbuf [0,131072) (2x64KB) | A dbuf [131072,163840) (2x16KB)
    // A layout: [row 0..127][slot 0..7][16B], slot = (kq*2+pl) ^ (row&7)
    // epilogue aliases: h_lds [0,65536) | w2t [65536,73728) | ls [73728,82432) | lsred=[0,65536)
    __shared__ __align__(16) char smem[163840];
    float* h_lds = (float*)smem;                 // [128][128]
    float* w2t   = (float*)(smem + 65536);       // [16][128]
    float* ls    = (float*)(smem + 73728);       // [128][17]
    float* lsred = (float*)smem;                 // [2048][8]

    const int tid  = threadIdx.x;
    const int wid  = tid >> 6;        // 0..15
    const int lane = tid & 63;
    const int l31  = lane & 31;
    const int lh   = lane >> 5;
    const int wm   = wid >> 3;        // 0..1  (m half)
    const int wn   = wid & 7;         // 0..7  (n eighth)
    const int m0   = blockIdx.x * BM;
    const int sgm  = l31 & 7;

    const int tq  = tid & 31;
    const int egq = (tid >> 5) & 3;
    const int ns  = tid >> 7;         // 0..7 (16-n slices)

    const int arow = (tid >> 2) & 127, kq = tid & 3;
    const int asg  = arow & 7;
    const bool astage = (tid < 512);

    float lacc[4][4];
    #pragma unroll
    for (int i = 0; i < 4; ++i)
        #pragma unroll
        for (int e = 0; e < 4; ++e) lacc[i][e] = 0.f;

    for (int p = 0; p < NPASS; ++p) {
        f32x16 acc[2][2];
        #pragma unroll
        for (int mf = 0; mf < 2; ++mf)
            #pragma unroll
            for (int nf = 0; nf < 2; ++nf)
                #pragma unroll
                for (int q = 0; q < 16; ++q) acc[mf][nf][q] = 0.f;

        // ---- prologue: stage 0 into buf 0 ----
        {
            const char* img = wimg + ((size_t)(0 * 2 + p) << 16);
            #pragma unroll
            for (int i = 0; i < 4; ++i) {
                int seg = (wid << 2) + i;
                gload_lds16(img + (seg << 10) + (lane << 4), smem + (seg << 10));
            }
            if (astage) {
                const float* xp = x + (size_t)(m0 + arow) * DM + kq * 8;
                float4 u = *(const float4*)xp;
                float4 v = *(const float4*)(xp + 4);
                f16x8 hi, lo;
                cvt_split8(u, v, hi, lo);
                char* ab = smem + 131072;
                *(f16x8*)(ab + (arow * 8 + ((kq * 2 + 0) ^ asg)) * 16) = hi;
                *(f16x8*)(ab + (arow * 8 + ((kq * 2 + 1) ^ asg)) * 16) = lo;
            }
        }
        __syncthreads();   // stage 0 visible (vmcnt+lgkm drained)

        for (int s = 0; s < NSTAGE; ++s) {
            const int cur = s & 1;
            float4 xu, xv;
            // ---- issue next-stage B-DMA + x-load BEFORE compute ----
            if (s < NSTAGE - 1) {
                const char* img = wimg + ((size_t)((s + 1) * 2 + p) << 16);
                #pragma unroll
                for (int i = 0; i < 4; ++i) {
                    int seg = (wid << 2) + i;
                    gload_lds16(img + (seg << 10) + (lane << 4),
                                smem + ((cur ^ 1) << 16) + (seg << 10));
                }
                if (astage) {
                    const float* xp = x + (size_t)(m0 + arow) * DM + (s + 1) * BK + kq * 8;
                    xu = *(const float4*)xp;
                    xv = *(const float4*)(xp + 4);
                }
            }
            const char* bb = smem + (cur << 16);
            const char* ab = smem + 131072 + (cur << 14);

            // ---- compute ks=0 (chunks q = lh): term-major ----
            {
                const int q = lh;
                f16x8 ah[2], al[2], bh[2], bl[2];
                #pragma unroll
                for (int mf = 0; mf < 2; ++mf) {
                    int m = wm * 64 + mf * 32 + l31;
                    ah[mf] = *(const f16x8*)(ab + (m * 8 + ((q * 2 + 0) ^ sgm)) * 16);
                    al[mf] = *(const f16x8*)(ab + (m * 8 + ((q * 2 + 1) ^ sgm)) * 16);
                }
                #pragma unroll
                for (int nf = 0; nf < 2; ++nf) {
                    int n = wn * 64 + nf * 32 + l31;
                    bh[nf] = *(const f16x8*)(bb + ((q * 2 + 0) * 512 + n) * 16);
                    bl[nf] = *(const f16x8*)(bb + ((q * 2 + 1) * 512 + n) * 16);
                }
                #pragma unroll
                for (int mf = 0; mf < 2; ++mf)
                    #pragma unroll
                    for (int nf = 0; nf < 2; ++nf)
                        acc[mf][nf] = __builtin_amdgcn_mfma_f32_32x32x16_f16(ah[mf], bh[nf], acc[mf][nf], 0, 0, 0);
                #pragma unroll
                for (int mf = 0; mf < 2; ++mf)
                    #pragma unroll
                    for (int nf = 0; nf < 2; ++nf)
                        acc[mf][nf] = __builtin_amdgcn_mfma_f32_32x32x16_f16(ah[mf], bl[nf], acc[mf][nf], 0, 0, 0);
                #pragma unroll
                for (int mf = 0; mf < 2; ++mf)
                    #pragma unroll
                    for (int nf = 0; nf < 2; ++nf)
                        acc[mf][nf] = __builtin_amdgcn_mfma_f32_32x32x16_f16(al[mf], bh[nf], acc[mf][nf], 0, 0, 0);
            }
            // ---- A(s+1) staging between halves ----
            if (s < NSTAGE - 1 && astage) {
                f16x8 hi, lo;
                cvt_split8(xu, xv, hi, lo);
                char* abn = smem + 131072 + ((cur ^ 1) << 14);
                *(f16x8*)(abn + (arow * 8 + ((kq * 2 + 0) ^ asg)) * 16) = hi;
                *(f16x8*)(abn + (arow * 8 + ((kq * 2 + 1) ^ asg)) * 16) = lo;
            }
            // ---- compute ks=1 (chunks q = 2+lh): term-major ----
            {
                const int q = 2 + lh;
                f16x8 ah[2], al[2], bh[2], bl[2];
                #pragma unroll
                for (int mf = 0; mf < 2; ++mf) {
                    int m = wm * 64 + mf * 32 + l31;
                    ah[mf] = *(const f16x8*)(ab + (m * 8 + ((q * 2 + 0) ^ sgm)) * 16);
                    al[mf] = *(const f16x8*)(ab + (m * 8 + ((q * 2 + 1) ^ sgm)) * 16);
                }
                #pragma unroll
                for (int nf = 0; nf < 2; ++nf) {
                    int n = wn * 64 + nf * 32 + l31;
                    bh[nf] = *(const f16x8*)(bb + ((q * 2 + 0) * 512 + n) * 16);
                    bl[nf] = *(const f16x8*)(bb + ((q * 2 + 1) * 512 + n) * 16);
                }
                #pragma unroll
                for (int mf = 0; mf < 2; ++mf)
                    #pragma unroll
                    for (int nf = 0; nf < 2; ++nf)
                        acc[mf][nf] = __builtin_amdgcn_mfma_f32_32x32x16_f16(ah[mf], bh[nf], acc[mf][nf], 0, 0, 0);
                #pragma unroll
                for (int mf = 0; mf < 2; ++mf)
                    #pragma unroll
                    for (int nf = 0; nf < 2; ++nf)
                        acc[mf][nf] = __builtin_amdgcn_mfma_f32_32x32x16_f16(ah[mf], bl[nf], acc[mf][nf], 0, 0, 0);
                #pragma unroll
                for (int mf = 0; mf < 2; ++mf)
                    #pragma unroll
                    for (int nf = 0; nf < 2; ++nf)
                        acc[mf][nf] = __builtin_amdgcn_mfma_f32_32x32x16_f16(al[mf], bh[nf], acc[mf][nf], 0, 0, 0);
            }
            __syncthreads();  // drains vmcnt (DMA landed) + lgkm (A write visible)
        }
        __syncthreads();   // full drain before smem reuse as h_lds

        // ---- pass epilogue: descale + bias + relu -> h chunks, fused GEMM2 (fp32) ----
        for (int ch = 0; ch < 4; ++ch) {
            __syncthreads();
            if ((wn >> 1) == ch) {
                #pragma unroll
                for (int nf = 0; nf < 2; ++nf) {
                    int col = (wn & 1) * 64 + nf * 32 + l31;
                    float bb2 = b1[p * BN + ch * 128 + col];
                    #pragma unroll
                    for (int mf = 0; mf < 2; ++mf)
                        #pragma unroll
                        for (int r = 0; r < 16; ++r) {
                            int row = wm * 64 + mf * 32 + (r & 3) + 8 * (r >> 2) + 4 * lh;
                            h_lds[row * 128 + col] = fmaxf(acc[mf][nf][r] * DESC + bb2, 0.f);
                        }
                }
            }
            #pragma unroll
            for (int q = 0; q < 2; ++q) {
                int i = tid * 2 + q;                    // 0..2047 = 128 n x 16 e
                int nn = i >> 4, e = i & 15;
                w2t[e * 128 + nn] = W2[(size_t)(p * BN + ch * 128 + nn) * NE + e];
            }
            __syncthreads();
            #pragma unroll
            for (int nn = 0; nn < 16; ++nn) {
                int nL = ns * 16 + ((nn + tq) & 15);    // staggered
                float hv[4], wv[4];
                #pragma unroll
                for (int i = 0; i < 4; ++i) hv[i] = h_lds[(tq * 4 + i) * 128 + nL];
                #pragma unroll
                for (int e = 0; e < 4; ++e) wv[e] = w2t[(egq * 4 + e) * 128 + nL];
                #pragma unroll
                for (int i = 0; i < 4; ++i)
                    #pragma unroll
                    for (int e = 0; e < 4; ++e)
                        lacc[i][e] = fmaf(hv[i], wv[e], lacc[i][e]);
            }
        }
        __syncthreads();  // protect smem before next-pass prologue DMA
    }

    // ---- reduce partial logits over 8 slices ----
    #pragma unroll
    for (int i = 0; i < 4; ++i)
        #pragma unroll
        for (int e = 0; e < 4; ++e)
            lsred[((tq * 4 + i) * 16 + egq * 4 + e) * 8 + ns] = lacc[i][e];
    __syncthreads();
    #pragma unroll
    for (int q = 0; q < 2; ++q) {
        int idx = tid * 2 + q;                          // 0..2047 = 128 t x 16 e
        int t = idx >> 4, e = idx & 15;
        float ssum = 0.f;
        #pragma unroll
        for (int sl = 0; sl < 8; ++sl) ssum += lsred[idx * 8 + sl];
        ls[t * 17 + e] = ssum + b2[e];
    }
    __syncthreads();

    // ---- softmax + top2 + flag ----
    if (tid < BM) {
        int t = tid;
        float l[NE]; float mx = -1e30f;
        #pragma unroll
        for (int e = 0; e < NE; ++e) { l[e] = ls[t * 17 + e]; mx = fmaxf(mx, l[e]); }
        float pb[NE]; float ssum = 0.f;
        #pragma unroll
        for (int e = 0; e < NE; ++e) { pb[e] = expf(l[e] - mx); ssum += pb[e]; }
        float inv = 1.f / ssum;
        #pragma unroll
        for (int e = 0; e < NE; ++e) pb[e] *= inv;

        int i1 = 0; float p1 = pb[0];
        #pragma unroll
        for (int e = 1; e < NE; ++e) if (pb[e] > p1) { p1 = pb[e]; i1 = e; }
        int i2 = -1; float p2 = -1.f;
        #pragma unroll
        for (int e = 0; e < NE; ++e) if (e != i1 && pb[e] > p2) { p2 = pb[e]; i2 = e; }
        float p3 = -1.f;
        #pragma unroll
        for (int e = 0; e < NE; ++e) if (e != i1 && e != i2 && pb[e] > p3) p3 = pb[e];

        float denom = p1 + p2 + 1e-8f;
        size_t gt = (size_t)(m0 + t);
        out[gt * 2 + 0] = p1 / denom;
        out[gt * 2 + 1] = p2 / denom;
        out[OFF_IDX + gt * 2 + 0] = (float)i1;
        out[OFF_IDX + gt * 2 + 1] = (float)i2;
        #pragma unroll
        for (int e = 0; e < NE; ++e) out[OFF_PROB + gt * 16 + e] = pb[e];

        if (p1 - p2 < RT_TAU || p2 - p3 < RT_TAU) {
            int k = atomicAdd(cnt, 1);
            list[k] = m0 + t;
        }
    }
}

// ---------------- fast repair: split-k partials (128 groups x 4 k-slices) ----------------
__global__ __launch_bounds__(256, 4)
void repair_partial(const float* __restrict__ x, const float* __restrict__ W1,
                    const int* __restrict__ cnt, const int* __restrict__ list,
                    float* __restrict__ hpart)
{
    __shared__ float xsl[4][512];
    __shared__ int tokid[4];
    const int tid = threadIdx.x;
    int nrep = cnt[0]; if (nrep > RCAP) nrep = RCAP;
    const int g = blockIdx.x >> 2, ks = blockIdx.x & 3;
    if (g * 4 >= nrep) return;

    if (tid < 4) {
        int j = g * 4 + tid;
        tokid[tid] = list[j < nrep ? j : 0];
    }
    __syncthreads();
    #pragma unroll
    for (int i = 0; i < 2; ++i) {
        int slot = tid + i * 256;
        int t = slot >> 7, c = slot & 127;
        *(float4*)(&xsl[t][c * 4]) =
            *(const float4*)(x + (size_t)tokid[t] * DM + ks * 512 + c * 4);
    }
    __syncthreads();

    float acc[4][4];
    #pragma unroll
    for (int t = 0; t < 4; ++t)
        #pragma unroll
        for (int q = 0; q < 4; ++q) acc[t][q] = 0.f;

    for (int k4 = 0; k4 < 128; ++k4) {
        float4 xv[4];
        #pragma unroll
        for (int t = 0; t < 4; ++t) xv[t] = *(const float4*)(&xsl[t][k4 * 4]);
        #pragma unroll
        for (int kk = 0; kk < 4; ++kk) {
            const float4 w = *(const float4*)(W1 + (size_t)(ks * 512 + k4 * 4 + kk) * DH + tid * 4);
            #pragma unroll
            for (int t = 0; t < 4; ++t) {
                const float a = ((const float*)&xv[t])[kk];
                acc[t][0] = fmaf(a, w.x, acc[t][0]);
                acc[t][1] = fmaf(a, w.y, acc[t][1]);
                acc[t][2] = fmaf(a, w.z, acc[t][2]);
                acc[t][3] = fmaf(a, w.w, acc[t][3]);
            }
        }
    }
    #pragma unroll
    for (int t = 0; t < 4; ++t)
        *(float4*)(hpart + (size_t)(g * 16 + ks * 4 + t) * 1024 + tid * 4) =
            make_float4(acc[t][0], acc[t][1], acc[t][2], acc[t][3]);
}

__global__ __launch_bounds__(256, 2)
void repair_final(const float* __restrict__ hpart, const float* __restrict__ b1,
                  const float* __restrict__ W2, const float* __restrict__ b2,
                  float* __restrict__ out,
                  const int* __restrict__ cnt, const int* __restrict__ list)
{
    __shared__ float hsh[4][DH];
    __shared__ float red[256];
    __shared__ float lg[4][NE];
    __shared__ int tokid[4];
    const int tid = threadIdx.x;
    int nrep = cnt[0]; if (nrep > RCAP) nrep = RCAP;
    const int g = blockIdx.x;
    if (g * 4 >= nrep) return;

    if (tid < 4) {
        int j = g * 4 + tid;
        tokid[tid] = list[j < nrep ? j : 0];
    }
    __syncthreads();
    #pragma unroll
    for (int i = 0; i < 4; ++i) {
        int slot = tid + i * 256;
        int t = slot >> 8, c = slot & 255;
        float4 s0 = *(const float4*)(hpart + (size_t)(g * 16 + 0 * 4 + t) * 1024 + c * 4);
        float4 s1 = *(const float4*)(hpart + (size_t)(g * 16 + 1 * 4 + t) * 1024 + c * 4);
        float4 s2 = *(const float4*)(hpart + (size_t)(g * 16 + 2 * 4 + t) * 1024 + c * 4);
        float4 s3 = *(const float4*)(hpart + (size_t)(g * 16 + 3 * 4 + t) * 1024 + c * 4);
        float4 bv = *(const float4*)(b1 + c * 4);
        float4 h;
        h.x = fmaxf(s0.x + s1.x + s2.x + s3.x + bv.x, 0.f);
        h.y = fmaxf(s0.y + s1.y + s2.y + s3.y + bv.y, 0.f);
        h.z = fmaxf(s0.z + s1.z + s2.z + s3.z + bv.z, 0.f);
        h.w = fmaxf(s0.w + s1.w + s2.w + s3.w + bv.w, 0.f);
        *(float4*)(&hsh[t][c * 4]) = h;
    }
    __syncthreads();
    {
        const int e  = tid & 15;
        const int t  = (tid >> 4) & 3;
        const int sl = tid >> 6;
        float ps = 0.f;
        for (int q = 0; q < 256; ++q) {
            int n = sl * 256 + q;
            ps = fmaf(hsh[t][n], W2[n * NE + e], ps);
        }
        red[tid] = ps;
    }
    __syncthreads();
    if (tid < 64) {
        int t = tid >> 4, e = tid & 15;
        lg[t][e] = b2[e] + red[0 * 64 + t * 16 + e] + red[1 * 64 + t * 16 + e]
                         + red[2 * 64 + t * 16 + e] + red[3 * 64 + t * 16 + e];
    }
    __syncthreads();
    if (tid < 4 && g * 4 + tid < nrep) {
        const int t = tid;
        float l[NE]; float mx = -1e30f;
        #pragma unroll
        for (int e = 0; e < NE; ++e) { l[e] = lg[t][e]; mx = fmaxf(mx, l[e]); }
        float pb[NE]; float ssum = 0.f;
        #pragma unroll
        for (int e = 0; e < NE; ++e) { pb[e] = expf(l[e] - mx); ssum += pb[e]; }
        float inv = 1.f / ssum;
        #pragma unroll
        for (int e = 0; e < NE; ++e) pb[e] *= inv;
        int i1 = 0; float p1 = pb[0];
        #pragma unroll
        for (int e = 1; e < NE; ++e) if (pb[e] > p1) { p1 = pb[e]; i1 = e; }
        int i2 = -1; float p2 = -1.f;
        #pragma unroll
        for (int e = 0; e < NE; ++e) if (e != i1 && pb[e] > p2) { p2 = pb[e]; i2 = e; }
        float denom = p1 + p2 + 1e-8f;
        size_t gt = (size_t)tokid[t];
        out[gt * 2 + 0] = p1 / denom;
        out[gt * 2 + 1] = p2 / denom;
        out[OFF_IDX + gt * 2 + 0] = (float)i1;
        out[OFF_IDX + gt * 2 + 1] = (float)i2;
        #pragma unroll
        for (int e = 0; e < NE; ++e) out[OFF_PROB + gt * 16 + e] = pb[e];
    }
}

// ---------------- repair4: full exact recompute (overflow backstop + fallback) ----------------
__global__ __launch_bounds__(256, 3)
void repair4(const float* __restrict__ x, const float* __restrict__ W1,
             const float* __restrict__ b1, const float* __restrict__ W2,
             const float* __restrict__ b2, float* __restrict__ out,
             const int* __restrict__ cnt, const int* __restrict__ list, int g0)
{
    __shared__ float xsh[4][DM];
    __shared__ float hsh[4][DH];
    __shared__ float red[256];
    __shared__ float lg[4][NE];
    __shared__ int   tokid[4];

    const int tid  = threadIdx.x;
    const int nrep = cnt[0];

    for (int g = g0 + blockIdx.x; g * 4 < nrep; g += gridDim.x) {
        __syncthreads();
        if (tid < 4) {
            int j = g * 4 + tid;
            tokid[tid] = list[j < nrep ? j : 0];
        }
        __syncthreads();
        #pragma unroll
        for (int i = 0; i < 8; ++i) {
            int slot = tid + i * 256;
            int t = slot >> 9, c = slot & 511;
            *(float4*)(&xsh[t][c * 4]) =
                *(const float4*)(x + (size_t)tokid[t] * DM + c * 4);
        }
        __syncthreads();

        float acc[4][4];
        #pragma unroll
        for (int t = 0; t < 4; ++t)
            #pragma unroll
            for (int q = 0; q < 4; ++q) acc[t][q] = 0.f;

        for (int k4 = 0; k4 < DM / 4; ++k4) {
            float4 xv[4];
            #pragma unroll
            for (int t = 0; t < 4; ++t) xv[t] = *(const float4*)(&xsh[t][k4 * 4]);
            #pragma unroll
            for (int kk = 0; kk < 4; ++kk) {
                const float4 w = *(const float4*)(W1 + (size_t)(k4 * 4 + kk) * DH + tid * 4);
                #pragma unroll
                for (int t = 0; t < 4; ++t) {
                    const float a = ((const float*)&xv[t])[kk];
                    acc[t][0] = fmaf(a, w.x, acc[t][0]);
                    acc[t][1] = fmaf(a, w.y, acc[t][1]);
                    acc[t][2] = fmaf(a, w.z, acc[t][2]);
                    acc[t][3] = fmaf(a, w.w, acc[t][3]);
                }
            }
        }
        {
            const float4 bv = *(const float4*)(b1 + tid * 4);
            #pragma unroll
            for (int t = 0; t < 4; ++t) {
                float4 h;
                h.x = fmaxf(acc[t][0] + bv.x, 0.f);
                h.y = fmaxf(acc[t][1] + bv.y, 0.f);
                h.z = fmaxf(acc[t][2] + bv.z, 0.f);
                h.w = fmaxf(acc[t][3] + bv.w, 0.f);
                *(float4*)(&hsh[t][tid * 4]) = h;
            }
        }
        __syncthreads();
        {
            const int e  = tid & 15;
            const int t  = (tid >> 4) & 3;
            const int sl = tid >> 6;
            float ps = 0.f;
            for (int q = 0; q < 256; ++q) {
                int n = sl * 256 + q;
                ps = fmaf(hsh[t][n], W2[n * NE + e], ps);
            }
            red[tid] = ps;
        }
        __syncthreads();
        if (tid < 64) {
            int t = tid >> 4, e = tid & 15;
            lg[t][e] = b2[e] + red[0 * 64 + t * 16 + e] + red[1 * 64 + t * 16 + e]
                             + red[2 * 64 + t * 16 + e] + red[3 * 64 + t * 16 + e];
        }
        __syncthreads();
        if (tid < 4 && g * 4 + tid < nrep) {
            const int t = tid;
            float l[NE]; float mx = -1e30f;
            #pragma unroll
            for (int e = 0; e < NE; ++e) { l[e] = lg[t][e]; mx = fmaxf(mx, l[e]); }
            float pb[NE]; float ssum = 0.f;
            #pragma unroll
            for (int e = 0; e < NE; ++e) { pb[e] = expf(l[e] - mx); ssum += pb[e]; }
            float inv = 1.f / ssum;
            #pragma unroll
            for (int e = 0; e < NE; ++e) pb[e] *= inv;
            int i1 = 0; float p1 = pb[0];
            #pragma unroll
            for (int e = 1; e < NE; ++e) if (pb[e] > p1) { p1 = pb[e]; i1 = e; }
            int i2 = -1; float p2 = -1.f;
            #pragma unroll
            for (int e = 0; e < NE; ++e) if (e != i1 && pb[e] > p2) { p2 = pb[e]; i2 = e; }
            float denom = p1 + p2 + 1e-8f;
            size_t gt = (size_t)tokid[t];
            out[gt * 2 + 0] = p1 / denom;
            out[gt * 2 + 1] = p2 / denom;
            out[OFF_IDX + gt * 2 + 0] = (float)i1;
            out[OFF_IDX + gt * 2 + 1] = (float)i2;
            #pragma unroll
            for (int e = 0; e < NE; ++e) out[OFF_PROB + gt * 16 + e] = pb[e];
        }
    }
}

// ---------------- fallback router (ws too small): R4-proven on-the-fly bf16 3-term ----------------
__global__ __launch_bounds__(512, 2)
void router_fb(const float* __restrict__ x, const float* __restrict__ W1,
               const float* __restrict__ b1, const float* __restrict__ W2,
               const float* __restrict__ b2, float* __restrict__ out,
               int* __restrict__ cnt, int* __restrict__ list)
{
    __shared__ short xs[128 * 64];
    __shared__ short bs[BN * 64];
    __shared__ float w2t[NE * 128];
    __shared__ float ls[128 * 17];

    float* h_lds = (float*)bs;
    float* lsred = (float*)bs;

    const int tid  = threadIdx.x;
    const int wid  = tid >> 6;
    const int lane = tid & 63;
    const int l31  = lane & 31;
    const int lh   = lane >> 5;
    const int sg   = lane & 7;
    const int wm   = wid >> 2;
    const int wn   = wid & 3;
    const int m0   = blockIdx.x * 128;

    const int tq  = tid & 31;
    const int egq = (tid >> 5) & 3;
    const int ns  = tid >> 7;

    float lacc[4][4];
    #pragma unroll
    for (int i = 0; i < 4; ++i)
        #pragma unroll
        for (int e = 0; e < 4; ++e) lacc[i][e] = 0.f;

    const int arow = tid >> 2, kq = tid & 3;
    const int asig = arow & 7;
    const int nloc = (wid << 6) + lane;
    const int sgl  = lane & 7;

    for (int p = 0; p < NPASS; ++p) {
        f32x16 acc[2][4];
        #pragma unroll
        for (int mf = 0; mf < 2; ++mf)
            #pragma unroll
            for (int nf = 0; nf < 4; ++nf)
                #pragma unroll
                for (int q = 0; q < 16; ++q) acc[mf][nf][q] = 0.f;

        for (int s = 0; s < 64; ++s) {
            __syncthreads();
            {
                const float* wp = W1 + (size_t)(s * 32) * DH + p * BN + nloc;
                short* rb = bs + nloc * 64;
                #pragma unroll
                for (int h = 0; h < 2; ++h) {
                    float f[16];
                    #pragma unroll
                    for (int j = 0; j < 16; ++j)
                        f[j] = wp[(size_t)(h * 16 + j) * DH];
                    uint32_t hd[8], ld_[8];
                    #pragma unroll
                    for (int q = 0; q < 8; ++q) {
                        uint32_t u0 = __float_as_uint(f[2 * q]);
                        uint32_t u1 = __float_as_uint(f[2 * q + 1]);
                        hd[q] = (u0 >> 16) | (u1 & 0xFFFF0000u);
                        float r0 = f[2 * q]     - __uint_as_float(u0 & 0xFFFF0000u);
                        float r1 = f[2 * q + 1] - __uint_as_float(u1 & 0xFFFF0000u);
                        ld_[q] = (__float_as_uint(r0) >> 16) | (__float_as_uint(r1) & 0xFFFF0000u);
                    }
                    *(int4*)(rb + (((2 * h + 0) ^ sgl) << 3)) = make_int4(hd[0], hd[1], hd[2], hd[3]);
                    *(int4*)(rb + (((2 * h + 1) ^ sgl) << 3)) = make_int4(hd[4], hd[5], hd[6], hd[7]);
                    *(int4*)(rb + (((4 + 2 * h + 0) ^ sgl) << 3)) = make_int4(ld_[0], ld_[1], ld_[2], ld_[3]);
                    *(int4*)(rb + (((4 + 2 * h + 1) ^ sgl) << 3)) = make_int4(ld_[4], ld_[5], ld_[6], ld_[7]);
                }
            }
            {
                const float* xp = x + (size_t)(m0 + arow) * DM + s * 32 + kq * 8;
                float4 v0 = *(const float4*)xp;
                float4 v1 = *(const float4*)(xp + 4);
                float f[8] = {v0.x, v0.y, v0.z, v0.w, v1.x, v1.y, v1.z, v1.w};
                uint32_t hd[4], ld_[4];
                #pragma unroll
                for (int q = 0; q < 4; ++q) {
                    uint32_t u0 = __float_as_uint(f[2 * q]);
                    uint32_t u1 = __float_as_uint(f[2 * q + 1]);
                    hd[q] = (u0 >> 16) | (u1 & 0xFFFF0000u);
                    float r0 = f[2 * q]     - __uint_as_float(u0 & 0xFFFF0000u);
                    float r1 = f[2 * q + 1] - __uint_as_float(u1 & 0xFFFF0000u);
                    ld_[q] = (__float_as_uint(r0) >> 16) | (__float_as_uint(r1) & 0xFFFF0000u);
                }
                short* ra = xs + arow * 64;
                *(int4*)(ra + ((kq ^ asig) << 3))       = make_int4(hd[0], hd[1], hd[2], hd[3]);
                *(int4*)(ra + (((4 + kq) ^ asig) << 3)) = make_int4(ld_[0], ld_[1], ld_[2], ld_[3]);
            }
            __syncthreads();
            #pragma unroll
            for (int ks = 0; ks < 2; ++ks) {
                bf16x8 a0[2], a1[2], b0[4], b1f[4];
                #pragma unroll
                for (int mf = 0; mf < 2; ++mf) {
                    int base = (wm * 64 + mf * 32 + l31) * 64;
                    a0[mf] = *(const bf16x8*)(xs + base + (((ks * 2 + lh)) ^ sg) * 8);
                    a1[mf] = *(const bf16x8*)(xs + base + (((4 + ks * 2 + lh)) ^ sg) * 8);
                }
                #pragma unroll
                for (int nf = 0; nf < 4; ++nf) {
                    int base = (wn * 128 + nf * 32 + l31) * 64;
                    b0[nf]  = *(const bf16x8*)(bs + base + (((ks * 2 + lh)) ^ sg) * 8);
                    b1f[nf] = *(const bf16x8*)(bs + base + (((4 + ks * 2 + lh)) ^ sg) * 8);
                }
                #pragma unroll
                for (int mf = 0; mf < 2; ++mf)
                    #pragma unroll
                    for (int nf = 0; nf < 4; ++nf) {
                        acc[mf][nf] = __builtin_amdgcn_mfma_f32_32x32x16_bf16(a0[mf], b0[nf],  acc[mf][nf], 0, 0, 0);
                        acc[mf][nf] = __builtin_amdgcn_mfma_f32_32x32x16_bf16(a0[mf], b1f[nf], acc[mf][nf], 0, 0, 0);
                        acc[mf][nf] = __builtin_amdgcn_mfma_f32_32x32x16_bf16(a1[mf], b0[nf],  acc[mf][nf], 0, 0, 0);
                    }
            }
        }

        for (int ch = 0; ch < 4; ++ch) {
            __syncthreads();
            if (wn == ch) {
                #pragma unroll
                for (int nf = 0; nf < 4; ++nf) {
                    int col = nf * 32 + l31;
                    float bb = b1[p * BN + ch * 128 + col];
                    #pragma unroll
                    for (int mf = 0; mf < 2; ++mf)
                        #pragma unroll
                        for (int r = 0; r < 16; ++r) {
                            int row = wm * 64 + mf * 32 + (r & 3) + 8 * (r >> 2) + 4 * lh;
                            h_lds[row * 128 + col] = fmaxf(acc[mf][nf][r] + bb, 0.f);
                        }
                }
            }
            #pragma unroll
            for (int q = 0; q < 4; ++q) {
                int i = tid * 4 + q;
                int nn = i >> 4, e = i & 15;
                w2t[e * 128 + nn] = W2[(size_t)(p * BN + ch * 128 + nn) * NE + e];
            }
            __syncthreads();
            for (int nn = 0; nn < 32; ++nn) {
                int nL = ns * 32 + ((nn + tq) & 31);
                float hv[4], wv[4];
                #pragma unroll
                for (int i = 0; i < 4; ++i) hv[i] = h_lds[(tq * 4 + i) * 128 + nL];
                #pragma unroll
                for (int e = 0; e < 4; ++e) wv[e] = w2t[(egq * 4 + e) * 128 + nL];
                #pragma unroll
                for (int i = 0; i < 4; ++i)
                    #pragma unroll
                    for (int e = 0; e < 4; ++e)
                        lacc[i][e] = fmaf(hv[i], wv[e], lacc[i][e]);
            }
        }
    }

    __syncthreads();
    #pragma unroll
    for (int i = 0; i < 4; ++i)
        #pragma unroll
        for (int e = 0; e < 4; ++e)
            lsred[((tq * 4 + i) * 16 + egq * 4 + e) * 4 + ns] = lacc[i][e];
    __syncthreads();
    #pragma unroll
    for (int q = 0; q < 4; ++q) {
        int idx = tid * 4 + q;
        int t = idx >> 4, e = idx & 15;
        ls[t * 17 + e] = lsred[idx * 4 + 0] + lsred[idx * 4 + 1] +
                         lsred[idx * 4 + 2] + lsred[idx * 4 + 3] + b2[e];
    }
    __syncthreads();

    if (tid < 128) {
        int t = tid;
        float l[NE]; float mx = -1e30f;
        #pragma unroll
        for (int e = 0; e < NE; ++e) { l[e] = ls[t * 17 + e]; mx = fmaxf(mx, l[e]); }
        float pb[NE]; float ssum = 0.f;
        #pragma unroll
        for (int e = 0; e < NE; ++e) { pb[e] = expf(l[e] - mx); ssum += pb[e]; }
        float inv = 1.f / ssum;
        #pragma unroll
        for (int e = 0; e < NE; ++e) pb[e] *= inv;

        int i1 = 0; float p1 = pb[0];
        #pragma unroll
        for (int e = 1; e < NE; ++e) if (pb[e] > p1) { p1 = pb[e]; i1 = e; }
        int i2 = -1; float p2 = -1.f;
        #pragma unroll
        for (int e = 0; e < NE; ++e) if (e != i1 && pb[e] > p2) { p2 = pb[e]; i2 = e; }
        float p3 = -1.f;
        #pragma unroll
        for (int e = 0; e < NE; ++e) if (e != i1 && e != i2 && pb[e] > p3) p3 = pb[e];

        float denom = p1 + p2 + 1e-8f;
        size_t gt = (size_t)(m0 + t);
        out[gt * 2 + 0] = p1 / denom;
        out[gt * 2 + 1] = p2 / denom;
        out[OFF_IDX + gt * 2 + 0] = (float)i1;
        out[OFF_IDX + gt * 2 + 1] = (float)i2;
        #pragma unroll
        for (int e = 0; e < NE; ++e) out[OFF_PROB + gt * 16 + e] = pb[e];

        if (p1 - p2 < FB_TAU || p2 - p3 < FB_TAU) {
            int k = atomicAdd(cnt, 1);
            list[k] = m0 + t;
        }
    }
}

extern "C" void kernel_launch(void* const* d_in, const int* in_sizes, int n_in,
                              void* d_out, int out_size, void* d_ws, size_t ws_size,
                              hipStream_t stream) {
    const float* x  = (const float*)d_in[0];
    const float* W1 = (const float*)d_in[1];
    const float* b1 = (const float*)d_in[2];
    const float* W2 = (const float*)d_in[3];
    const float* b2 = (const float*)d_in[4];
    float* out = (float*)d_out;

    int*   cnt   = (int*)d_ws;
    int*   list  = (int*)((char*)d_ws + WS_LIST);
    char*  wimg  = (char*)d_ws + WS_WT;
    float* hpart = (float*)wimg;   // repair partials alias wimg (used after router)

    hipMemsetAsync(cnt, 0, sizeof(int), stream);
    if (ws_size >= WS_NEEDED) {
        hipLaunchKernelGGL(prep_w16, dim3(NSTAGE * NPASS), dim3(256), 0, stream, W1, wimg);
        hipLaunchKernelGGL(router16, dim3(TOKENS / BM), dim3(1024), 0, stream,
                           x, wimg, b1, W2, b2, out, cnt, list);
        hipLaunchKernelGGL(repair_partial, dim3(512), dim3(256), 0, stream,
                           x, W1, cnt, list, hpart);
        hipLaunchKernelGGL(repair_final, dim3(128), dim3(256), 0, stream,
                           hpart, b1, W2, b2, out, cnt, list);
        hipLaunchKernelGGL(repair4, dim3(128), dim3(256), 0, stream,
                           x, W1, b1, W2, b2, out, cnt, list, RCAP / 4);
    } else {
        hipLaunchKernelGGL(router_fb, dim3(TOKENS / 128), dim3(512), 0, stream,
                           x, W1, b1, W2, b2, out, cnt, list);
        hipLaunchKernelGGL(repair4, dim3(512), dim3(256), 0, stream,
                           x, W1, b1, W2, b2, out, cnt, list, 0);
    }
}

// Round 15
// 479.592 us; speedup vs baseline: 1.7048x; 1.7048x over previous
//
#include <hip/hip_runtime.h>
#include <math.h>
#include <stdint.h>

#define TOKENS 32768
#define DM 2048
#define DH 1024
#define NE 16
#define BM 128
#define BN 512
#define NPASS 2
#define BK 32
#define NSTAGE 64              // DM / BK
#define RT_TAU 5e-5f
#define FB_TAU 5e-4f
#define XSC 16.0f              // x pre-scale (2^4)
#define WSC 64.0f              // W pre-scale (2^6)
#define DESC (1.0f/1024.0f)    // acc descale (2^-10)

// output layout (floats): gates[T*2] | indices[T*2] | probs[T*16]
#define OFF_IDX  (TOKENS * 2)
#define OFF_PROB (TOKENS * 4)

// ws layout: [0] cnt | [1024] list (32768 int) | [132096] wimg (8 MB fp16 hi/lo image)
#define WS_LIST 1024
#define WS_WT   132096
#define WIMG_BYTES ((size_t)NSTAGE * NPASS * 65536)     // 8 MB
#define WS_NEEDED ((size_t)WS_WT + WIMG_BYTES)
#define RCAP 512

typedef _Float16 f16x8 __attribute__((ext_vector_type(8)));
typedef short    bf16x8 __attribute__((ext_vector_type(8)));
typedef float    f32x16 __attribute__((ext_vector_type(16)));

static __device__ __forceinline__ void gload_lds16(const void* g, void* l) {
    __builtin_amdgcn_global_load_lds(
        (const __attribute__((address_space(1))) void*)g,
        (__attribute__((address_space(3))) void*)l, 16, 0, 0);
}

// split 8 scaled floats into fp16 hi + residual lo
static __device__ __forceinline__ void cvt_split8(float4 u, float4 v, f16x8& hi, f16x8& lo) {
    float f[8] = {u.x * XSC, u.y * XSC, u.z * XSC, u.w * XSC,
                  v.x * XSC, v.y * XSC, v.z * XSC, v.w * XSC};
    #pragma unroll
    for (int j = 0; j < 8; ++j) {
        _Float16 h = (_Float16)f[j];
        hi[j] = h;
        lo[j] = (_Float16)(f[j] - (float)h);
    }
}

// ---------------- prep: W1 -> per-stage LDS byte image (64 KB each) ----------------
// image id = s*2+p (s in 0..63). Layout: [q 0..3][pl 0..1][n 0..511][8 fp16];
// byte = ((q*2+pl)*512 + n)*16; chunk q holds k = s*32 + q*8 .. +7.
__global__ __launch_bounds__(256)
void prep_w16(const float* __restrict__ W1, char* __restrict__ wimg) {
    const int bid = blockIdx.x;            // 0..127
    const int s = bid >> 1, p = bid & 1;
    char* img = wimg + ((size_t)bid << 16);
    const int tid = threadIdx.x;
    #pragma unroll
    for (int rep = 0; rep < 2; ++rep) {
        const int n = tid + rep * 256;
        #pragma unroll
        for (int q = 0; q < 4; ++q) {
            f16x8 hi, lo;
            #pragma unroll
            for (int j = 0; j < 8; ++j) {
                float ww = W1[(size_t)(s * 32 + q * 8 + j) * DH + p * 512 + n] * WSC;
                _Float16 h = (_Float16)ww;
                hi[j] = h;
                lo[j] = (_Float16)(ww - (float)h);
            }
            *(f16x8*)(img + ((q * 2 + 0) * 512 + n) * 16) = hi;
            *(f16x8*)(img + ((q * 2 + 1) * 512 + n) * 16) = lo;
        }
    }
}

// ---------------- fused GEMM1 (fp16 3-term MFMA, BK=32, term-major MFMA order) ----------------
__global__ __launch_bounds__(512, 2)
void router16(const float* __restrict__ x, const char* __restrict__ wimg,
              const float* __restrict__ b1, const float* __restrict__ W2,
              const float* __restrict__ b2, float* __restrict__ out,
              int* __restrict__ cnt, int* __restrict__ list)
{
    // 160 KB exactly: B dbuf [0,131072) (2x64KB) | A dbuf [131072,163840) (2x16KB)
    // A layout: [row 0..127][slot 0..7][16B], slot = (kq*2+pl) ^ (row&7)  (XOR swizzle)
    // epilogue aliases: h_lds [0,65536) | w2t [65536,73728) | ls [73728,82432) | lsred=h_lds
    __shared__ __align__(16) char smem[163840];
    float* h_lds = (float*)smem;
    float* w2t   = (float*)(smem + 65536);
    float* ls    = (float*)(smem + 73728);
    float* lsred = (float*)smem;

    const int tid  = threadIdx.x;
    const int wid  = tid >> 6;
    const int lane = tid & 63;
    const int l31  = lane & 31;
    const int lh   = lane >> 5;
    const int wm   = wid >> 2;            // 0..1
    const int wn   = wid & 3;             // 0..3
    const int m0   = blockIdx.x * BM;
    const int sgm  = l31 & 7;             // row&7 for this lane's A rows

    const int tq  = tid & 31;
    const int egq = (tid >> 5) & 3;
    const int ns  = tid >> 7;

    const int arow = tid >> 2, kq = tid & 3;   // A staging: row 0..127, 8-k chunk 0..3
    const int asg  = arow & 7;

    float lacc[4][4];
    #pragma unroll
    for (int i = 0; i < 4; ++i)
        #pragma unroll
        for (int e = 0; e < 4; ++e) lacc[i][e] = 0.f;

    for (int p = 0; p < NPASS; ++p) {
        f32x16 acc[2][4];
        #pragma unroll
        for (int mf = 0; mf < 2; ++mf)
            #pragma unroll
            for (int nf = 0; nf < 4; ++nf)
                #pragma unroll
                for (int q = 0; q < 16; ++q) acc[mf][nf][q] = 0.f;

        // ---- prologue: stage 0 into buf 0 ----
        {
            const char* img = wimg + ((size_t)(0 * 2 + p) << 16);
            #pragma unroll
            for (int i = 0; i < 8; ++i) {
                int seg = (wid << 3) + i;
                gload_lds16(img + (seg << 10) + (lane << 4), smem + (seg << 10));
            }
            const float* xp = x + (size_t)(m0 + arow) * DM + kq * 8;
            float4 u = *(const float4*)xp;
            float4 v = *(const float4*)(xp + 4);
            f16x8 hi, lo;
            cvt_split8(u, v, hi, lo);
            char* ab = smem + 131072;
            *(f16x8*)(ab + (arow * 8 + ((kq * 2 + 0) ^ asg)) * 16) = hi;
            *(f16x8*)(ab + (arow * 8 + ((kq * 2 + 1) ^ asg)) * 16) = lo;
        }
        __syncthreads();   // stage 0 visible (vmcnt+lgkm drained)

        for (int s = 0; s < NSTAGE; ++s) {
            const int cur = s & 1;
            float4 xu, xv;
            // ---- issue next-stage B-DMA + x-load BEFORE compute ----
            if (s < NSTAGE - 1) {
                const char* img = wimg + ((size_t)((s + 1) * 2 + p) << 16);
                #pragma unroll
                for (int i = 0; i < 8; ++i) {
                    int seg = (wid << 3) + i;
                    gload_lds16(img + (seg << 10) + (lane << 4),
                                smem + ((cur ^ 1) << 16) + (seg << 10));
                }
                const float* xp = x + (size_t)(m0 + arow) * DM + (s + 1) * BK + kq * 8;
                xu = *(const float4*)xp;
                xv = *(const float4*)(xp + 4);
            }
            const char* bb = smem + (cur << 16);
            const char* ab = smem + 131072 + (cur << 14);

            // ---- compute ks=0 (chunks q = lh): term-major MFMA order ----
            {
                const int q = lh;
                f16x8 ah[2], al[2], bh[4], bl[4];
                #pragma unroll
                for (int mf = 0; mf < 2; ++mf) {
                    int m = wm * 64 + mf * 32 + l31;
                    ah[mf] = *(const f16x8*)(ab + (m * 8 + ((q * 2 + 0) ^ sgm)) * 16);
                    al[mf] = *(const f16x8*)(ab + (m * 8 + ((q * 2 + 1) ^ sgm)) * 16);
                }
                #pragma unroll
                for (int nf = 0; nf < 4; ++nf) {
                    int n = wn * 128 + nf * 32 + l31;
                    bh[nf] = *(const f16x8*)(bb + ((q * 2 + 0) * 512 + n) * 16);
                    bl[nf] = *(const f16x8*)(bb + ((q * 2 + 1) * 512 + n) * 16);
                }
                #pragma unroll
                for (int mf = 0; mf < 2; ++mf)
                    #pragma unroll
                    for (int nf = 0; nf < 4; ++nf)
                        acc[mf][nf] = __builtin_amdgcn_mfma_f32_32x32x16_f16(ah[mf], bh[nf], acc[mf][nf], 0, 0, 0);
                #pragma unroll
                for (int mf = 0; mf < 2; ++mf)
                    #pragma unroll
                    for (int nf = 0; nf < 4; ++nf)
                        acc[mf][nf] = __builtin_amdgcn_mfma_f32_32x32x16_f16(ah[mf], bl[nf], acc[mf][nf], 0, 0, 0);
                #pragma unroll
                for (int mf = 0; mf < 2; ++mf)
                    #pragma unroll
                    for (int nf = 0; nf < 4; ++nf)
                        acc[mf][nf] = __builtin_amdgcn_mfma_f32_32x32x16_f16(al[mf], bh[nf], acc[mf][nf], 0, 0, 0);
            }
            // ---- A(s+1) staging between halves (other buffer; prior readers done) ----
            if (s < NSTAGE - 1) {
                f16x8 hi, lo;
                cvt_split8(xu, xv, hi, lo);
                char* abn = smem + 131072 + ((cur ^ 1) << 14);
                *(f16x8*)(abn + (arow * 8 + ((kq * 2 + 0) ^ asg)) * 16) = hi;
                *(f16x8*)(abn + (arow * 8 + ((kq * 2 + 1) ^ asg)) * 16) = lo;
            }
            // ---- compute ks=1 (chunks q = 2+lh): term-major MFMA order ----
            {
                const int q = 2 + lh;
                f16x8 ah[2], al[2], bh[4], bl[4];
                #pragma unroll
                for (int mf = 0; mf < 2; ++mf) {
                    int m = wm * 64 + mf * 32 + l31;
                    ah[mf] = *(const f16x8*)(ab + (m * 8 + ((q * 2 + 0) ^ sgm)) * 16);
                    al[mf] = *(const f16x8*)(ab + (m * 8 + ((q * 2 + 1) ^ sgm)) * 16);
                }
                #pragma unroll
                for (int nf = 0; nf < 4; ++nf) {
                    int n = wn * 128 + nf * 32 + l31;
                    bh[nf] = *(const f16x8*)(bb + ((q * 2 + 0) * 512 + n) * 16);
                    bl[nf] = *(const f16x8*)(bb + ((q * 2 + 1) * 512 + n) * 16);
                }
                #pragma unroll
                for (int mf = 0; mf < 2; ++mf)
                    #pragma unroll
                    for (int nf = 0; nf < 4; ++nf)
                        acc[mf][nf] = __builtin_amdgcn_mfma_f32_32x32x16_f16(ah[mf], bh[nf], acc[mf][nf], 0, 0, 0);
                #pragma unroll
                for (int mf = 0; mf < 2; ++mf)
                    #pragma unroll
                    for (int nf = 0; nf < 4; ++nf)
                        acc[mf][nf] = __builtin_amdgcn_mfma_f32_32x32x16_f16(ah[mf], bl[nf], acc[mf][nf], 0, 0, 0);
                #pragma unroll
                for (int mf = 0; mf < 2; ++mf)
                    #pragma unroll
                    for (int nf = 0; nf < 4; ++nf)
                        acc[mf][nf] = __builtin_amdgcn_mfma_f32_32x32x16_f16(al[mf], bh[nf], acc[mf][nf], 0, 0, 0);
            }
            __syncthreads();  // drains vmcnt (DMA landed) + lgkm (A write visible)
        }
        __syncthreads();   // full drain before smem reuse as h_lds

        // ---- pass epilogue: descale + bias + relu -> h chunks, fused GEMM2 (fp32) ----
        for (int ch = 0; ch < 4; ++ch) {
            __syncthreads();
            if (wn == ch) {
                #pragma unroll
                for (int nf = 0; nf < 4; ++nf) {
                    int col = nf * 32 + l31;
                    float bb2 = b1[p * BN + ch * 128 + col];
                    #pragma unroll
                    for (int mf = 0; mf < 2; ++mf)
                        #pragma unroll
                        for (int r = 0; r < 16; ++r) {
                            int row = wm * 64 + mf * 32 + (r & 3) + 8 * (r >> 2) + 4 * lh;
                            h_lds[row * 128 + col] = fmaxf(acc[mf][nf][r] * DESC + bb2, 0.f);
                        }
                }
            }
            #pragma unroll
            for (int q = 0; q < 4; ++q) {
                int i = tid * 4 + q;                    // 0..2047 = 128 n x 16 e
                int nn = i >> 4, e = i & 15;
                w2t[e * 128 + nn] = W2[(size_t)(p * BN + ch * 128 + nn) * NE + e];
            }
            __syncthreads();
            for (int nn = 0; nn < 32; ++nn) {
                int nL = ns * 32 + ((nn + tq) & 31);    // staggered: conflict-free
                float hv[4], wv[4];
                #pragma unroll
                for (int i = 0; i < 4; ++i) hv[i] = h_lds[(tq * 4 + i) * 128 + nL];
                #pragma unroll
                for (int e = 0; e < 4; ++e) wv[e] = w2t[(egq * 4 + e) * 128 + nL];
                #pragma unroll
                for (int i = 0; i < 4; ++i)
                    #pragma unroll
                    for (int e = 0; e < 4; ++e)
                        lacc[i][e] = fmaf(hv[i], wv[e], lacc[i][e]);
            }
        }
        __syncthreads();  // protect smem before next-pass prologue DMA
    }

    // ---- reduce partial logits ----
    #pragma unroll
    for (int i = 0; i < 4; ++i)
        #pragma unroll
        for (int e = 0; e < 4; ++e)
            lsred[((tq * 4 + i) * 16 + egq * 4 + e) * 4 + ns] = lacc[i][e];
    __syncthreads();
    #pragma unroll
    for (int q = 0; q < 4; ++q) {
        int idx = tid * 4 + q;
        int t = idx >> 4, e = idx & 15;
        ls[t * 17 + e] = lsred[idx * 4 + 0] + lsred[idx * 4 + 1] +
                         lsred[idx * 4 + 2] + lsred[idx * 4 + 3] + b2[e];
    }
    __syncthreads();

    // ---- softmax + top2 + flag ----
    if (tid < BM) {
        int t = tid;
        float l[NE]; float mx = -1e30f;
        #pragma unroll
        for (int e = 0; e < NE; ++e) { l[e] = ls[t * 17 + e]; mx = fmaxf(mx, l[e]); }
        float pb[NE]; float ssum = 0.f;
        #pragma unroll
        for (int e = 0; e < NE; ++e) { pb[e] = expf(l[e] - mx); ssum += pb[e]; }
        float inv = 1.f / ssum;
        #pragma unroll
        for (int e = 0; e < NE; ++e) pb[e] *= inv;

        int i1 = 0; float p1 = pb[0];
        #pragma unroll
        for (int e = 1; e < NE; ++e) if (pb[e] > p1) { p1 = pb[e]; i1 = e; }
        int i2 = -1; float p2 = -1.f;
        #pragma unroll
        for (int e = 0; e < NE; ++e) if (e != i1 && pb[e] > p2) { p2 = pb[e]; i2 = e; }
        float p3 = -1.f;
        #pragma unroll
        for (int e = 0; e < NE; ++e) if (e != i1 && e != i2 && pb[e] > p3) p3 = pb[e];

        float denom = p1 + p2 + 1e-8f;
        size_t gt = (size_t)(m0 + t);
        out[gt * 2 + 0] = p1 / denom;
        out[gt * 2 + 1] = p2 / denom;
        out[OFF_IDX + gt * 2 + 0] = (float)i1;
        out[OFF_IDX + gt * 2 + 1] = (float)i2;
        #pragma unroll
        for (int e = 0; e < NE; ++e) out[OFF_PROB + gt * 16 + e] = pb[e];

        if (p1 - p2 < RT_TAU || p2 - p3 < RT_TAU) {
            int k = atomicAdd(cnt, 1);
            list[k] = m0 + t;
        }
    }
}

// ---------------- fast repair: split-k partials (128 groups x 4 k-slices) ----------------
__global__ __launch_bounds__(256, 4)
void repair_partial(const float* __restrict__ x, const float* __restrict__ W1,
                    const int* __restrict__ cnt, const int* __restrict__ list,
                    float* __restrict__ hpart)
{
    __shared__ float xsl[4][512];
    __shared__ int tokid[4];
    const int tid = threadIdx.x;
    int nrep = cnt[0]; if (nrep > RCAP) nrep = RCAP;
    const int g = blockIdx.x >> 2, ks = blockIdx.x & 3;
    if (g * 4 >= nrep) return;

    if (tid < 4) {
        int j = g * 4 + tid;
        tokid[tid] = list[j < nrep ? j : 0];
    }
    __syncthreads();
    #pragma unroll
    for (int i = 0; i < 2; ++i) {
        int slot = tid + i * 256;
        int t = slot >> 7, c = slot & 127;
        *(float4*)(&xsl[t][c * 4]) =
            *(const float4*)(x + (size_t)tokid[t] * DM + ks * 512 + c * 4);
    }
    __syncthreads();

    float acc[4][4];
    #pragma unroll
    for (int t = 0; t < 4; ++t)
        #pragma unroll
        for (int q = 0; q < 4; ++q) acc[t][q] = 0.f;

    for (int k4 = 0; k4 < 128; ++k4) {
        float4 xv[4];
        #pragma unroll
        for (int t = 0; t < 4; ++t) xv[t] = *(const float4*)(&xsl[t][k4 * 4]);
        #pragma unroll
        for (int kk = 0; kk < 4; ++kk) {
            const float4 w = *(const float4*)(W1 + (size_t)(ks * 512 + k4 * 4 + kk) * DH + tid * 4);
            #pragma unroll
            for (int t = 0; t < 4; ++t) {
                const float a = ((const float*)&xv[t])[kk];
                acc[t][0] = fmaf(a, w.x, acc[t][0]);
                acc[t][1] = fmaf(a, w.y, acc[t][1]);
                acc[t][2] = fmaf(a, w.z, acc[t][2]);
                acc[t][3] = fmaf(a, w.w, acc[t][3]);
            }
        }
    }
    #pragma unroll
    for (int t = 0; t < 4; ++t)
        *(float4*)(hpart + (size_t)(g * 16 + ks * 4 + t) * 1024 + tid * 4) =
            make_float4(acc[t][0], acc[t][1], acc[t][2], acc[t][3]);
}

__global__ __launch_bounds__(256, 2)
void repair_final(const float* __restrict__ hpart, const float* __restrict__ b1,
                  const float* __restrict__ W2, const float* __restrict__ b2,
                  float* __restrict__ out,
                  const int* __restrict__ cnt, const int* __restrict__ list)
{
    __shared__ float hsh[4][DH];
    __shared__ float red[256];
    __shared__ float lg[4][NE];
    __shared__ int tokid[4];
    const int tid = threadIdx.x;
    int nrep = cnt[0]; if (nrep > RCAP) nrep = RCAP;
    const int g = blockIdx.x;
    if (g * 4 >= nrep) return;

    if (tid < 4) {
        int j = g * 4 + tid;
        tokid[tid] = list[j < nrep ? j : 0];
    }
    __syncthreads();
    #pragma unroll
    for (int i = 0; i < 4; ++i) {
        int slot = tid + i * 256;
        int t = slot >> 8, c = slot & 255;
        float4 s0 = *(const float4*)(hpart + (size_t)(g * 16 + 0 * 4 + t) * 1024 + c * 4);
        float4 s1 = *(const float4*)(hpart + (size_t)(g * 16 + 1 * 4 + t) * 1024 + c * 4);
        float4 s2 = *(const float4*)(hpart + (size_t)(g * 16 + 2 * 4 + t) * 1024 + c * 4);
        float4 s3 = *(const float4*)(hpart + (size_t)(g * 16 + 3 * 4 + t) * 1024 + c * 4);
        float4 bv = *(const float4*)(b1 + c * 4);
        float4 h;
        h.x = fmaxf(s0.x + s1.x + s2.x + s3.x + bv.x, 0.f);
        h.y = fmaxf(s0.y + s1.y + s2.y + s3.y + bv.y, 0.f);
        h.z = fmaxf(s0.z + s1.z + s2.z + s3.z + bv.z, 0.f);
        h.w = fmaxf(s0.w + s1.w + s2.w + s3.w + bv.w, 0.f);
        *(float4*)(&hsh[t][c * 4]) = h;
    }
    __syncthreads();
    {
        const int e  = tid & 15;
        const int t  = (tid >> 4) & 3;
        const int sl = tid >> 6;
        float ps = 0.f;
        for (int q = 0; q < 256; ++q) {
            int n = sl * 256 + q;
            ps = fmaf(hsh[t][n], W2[n * NE + e], ps);
        }
        red[tid] = ps;
    }
    __syncthreads();
    if (tid < 64) {
        int t = tid >> 4, e = tid & 15;
        lg[t][e] = b2[e] + red[0 * 64 + t * 16 + e] + red[1 * 64 + t * 16 + e]
                         + red[2 * 64 + t * 16 + e] + red[3 * 64 + t * 16 + e];
    }
    __syncthreads();
    if (tid < 4 && g * 4 + tid < nrep) {
        const int t = tid;
        float l[NE]; float mx = -1e30f;
        #pragma unroll
        for (int e = 0; e < NE; ++e) { l[e] = lg[t][e]; mx = fmaxf(mx, l[e]); }
        float pb[NE]; float ssum = 0.f;
        #pragma unroll
        for (int e = 0; e < NE; ++e) { pb[e] = expf(l[e] - mx); ssum += pb[e]; }
        float inv = 1.f / ssum;
        #pragma unroll
        for (int e = 0; e < NE; ++e) pb[e] *= inv;
        int i1 = 0; float p1 = pb[0];
        #pragma unroll
        for (int e = 1; e < NE; ++e) if (pb[e] > p1) { p1 = pb[e]; i1 = e; }
        int i2 = -1; float p2 = -1.f;
        #pragma unroll
        for (int e = 0; e < NE; ++e) if (e != i1 && pb[e] > p2) { p2 = pb[e]; i2 = e; }
        float denom = p1 + p2 + 1e-8f;
        size_t gt = (size_t)tokid[t];
        out[gt * 2 + 0] = p1 / denom;
        out[gt * 2 + 1] = p2 / denom;
        out[OFF_IDX + gt * 2 + 0] = (float)i1;
        out[OFF_IDX + gt * 2 + 1] = (float)i2;
        #pragma unroll
        for (int e = 0; e < NE; ++e) out[OFF_PROB + gt * 16 + e] = pb[e];
    }
}

// ---------------- repair4: full exact recompute (overflow backstop + fallback) ----------------
__global__ __launch_bounds__(256, 3)
void repair4(const float* __restrict__ x, const float* __restrict__ W1,
             const float* __restrict__ b1, const float* __restrict__ W2,
             const float* __restrict__ b2, float* __restrict__ out,
             const int* __restrict__ cnt, const int* __restrict__ list, int g0)
{
    __shared__ float xsh[4][DM];
    __shared__ float hsh[4][DH];
    __shared__ float red[256];
    __shared__ float lg[4][NE];
    __shared__ int   tokid[4];

    const int tid  = threadIdx.x;
    const int nrep = cnt[0];

    for (int g = g0 + blockIdx.x; g * 4 < nrep; g += gridDim.x) {
        __syncthreads();
        if (tid < 4) {
            int j = g * 4 + tid;
            tokid[tid] = list[j < nrep ? j : 0];
        }
        __syncthreads();
        #pragma unroll
        for (int i = 0; i < 8; ++i) {
            int slot = tid + i * 256;
            int t = slot >> 9, c = slot & 511;
            *(float4*)(&xsh[t][c * 4]) =
                *(const float4*)(x + (size_t)tokid[t] * DM + c * 4);
        }
        __syncthreads();

        float acc[4][4];
        #pragma unroll
        for (int t = 0; t < 4; ++t)
            #pragma unroll
            for (int q = 0; q < 4; ++q) acc[t][q] = 0.f;

        for (int k4 = 0; k4 < DM / 4; ++k4) {
            float4 xv[4];
            #pragma unroll
            for (int t = 0; t < 4; ++t) xv[t] = *(const float4*)(&xsh[t][k4 * 4]);
            #pragma unroll
            for (int kk = 0; kk < 4; ++kk) {
                const float4 w = *(const float4*)(W1 + (size_t)(k4 * 4 + kk) * DH + tid * 4);
                #pragma unroll
                for (int t = 0; t < 4; ++t) {
                    const float a = ((const float*)&xv[t])[kk];
                    acc[t][0] = fmaf(a, w.x, acc[t][0]);
                    acc[t][1] = fmaf(a, w.y, acc[t][1]);
                    acc[t][2] = fmaf(a, w.z, acc[t][2]);
                    acc[t][3] = fmaf(a, w.w, acc[t][3]);
                }
            }
        }
        {
            const float4 bv = *(const float4*)(b1 + tid * 4);
            #pragma unroll
            for (int t = 0; t < 4; ++t) {
                float4 h;
                h.x = fmaxf(acc[t][0] + bv.x, 0.f);
                h.y = fmaxf(acc[t][1] + bv.y, 0.f);
                h.z = fmaxf(acc[t][2] + bv.z, 0.f);
                h.w = fmaxf(acc[t][3] + bv.w, 0.f);
                *(float4*)(&hsh[t][tid * 4]) = h;
            }
        }
        __syncthreads();
        {
            const int e  = tid & 15;
            const int t  = (tid >> 4) & 3;
            const int sl = tid >> 6;
            float ps = 0.f;
            for (int q = 0; q < 256; ++q) {
                int n = sl * 256 + q;
                ps = fmaf(hsh[t][n], W2[n * NE + e], ps);
            }
            red[tid] = ps;
        }
        __syncthreads();
        if (tid < 64) {
            int t = tid >> 4, e = tid & 15;
            lg[t][e] = b2[e] + red[0 * 64 + t * 16 + e] + red[1 * 64 + t * 16 + e]
                             + red[2 * 64 + t * 16 + e] + red[3 * 64 + t * 16 + e];
        }
        __syncthreads();
        if (tid < 4 && g * 4 + tid < nrep) {
            const int t = tid;
            float l[NE]; float mx = -1e30f;
            #pragma unroll
            for (int e = 0; e < NE; ++e) { l[e] = lg[t][e]; mx = fmaxf(mx, l[e]); }
            float pb[NE]; float ssum = 0.f;
            #pragma unroll
            for (int e = 0; e < NE; ++e) { pb[e] = expf(l[e] - mx); ssum += pb[e]; }
            float inv = 1.f / ssum;
            #pragma unroll
            for (int e = 0; e < NE; ++e) pb[e] *= inv;
            int i1 = 0; float p1 = pb[0];
            #pragma unroll
            for (int e = 1; e < NE; ++e) if (pb[e] > p1) { p1 = pb[e]; i1 = e; }
            int i2 = -1; float p2 = -1.f;
            #pragma unroll
            for (int e = 0; e < NE; ++e) if (e != i1 && pb[e] > p2) { p2 = pb[e]; i2 = e; }
            float denom = p1 + p2 + 1e-8f;
            size_t gt = (size_t)tokid[t];
            out[gt * 2 + 0] = p1 / denom;
            out[gt * 2 + 1] = p2 / denom;
            out[OFF_IDX + gt * 2 + 0] = (float)i1;
            out[OFF_IDX + gt * 2 + 1] = (float)i2;
            #pragma unroll
            for (int e = 0; e < NE; ++e) out[OFF_PROB + gt * 16 + e] = pb[e];
        }
    }
}

// ---------------- fallback router (ws too small): R4-proven on-the-fly bf16 3-term ----------------
__global__ __launch_bounds__(512, 2)
void router_fb(const float* __restrict__ x, const float* __restrict__ W1,
               const float* __restrict__ b1, const float* __restrict__ W2,
               const float* __restrict__ b2, float* __restrict__ out,
               int* __restrict__ cnt, int* __restrict__ list)
{
    __shared__ short xs[128 * 64];
    __shared__ short bs[BN * 64];
    __shared__ float w2t[NE * 128];
    __shared__ float ls[128 * 17];

    float* h_lds = (float*)bs;
    float* lsred = (float*)bs;

    const int tid  = threadIdx.x;
    const int wid  = tid >> 6;
    const int lane = tid & 63;
    const int l31  = lane & 31;
    const int lh   = lane >> 5;
    const int sg   = lane & 7;
    const int wm   = wid >> 2;
    const int wn   = wid & 3;
    const int m0   = blockIdx.x * 128;

    const int tq  = tid & 31;
    const int egq = (tid >> 5) & 3;
    const int ns  = tid >> 7;

    float lacc[4][4];
    #pragma unroll
    for (int i = 0; i < 4; ++i)
        #pragma unroll
        for (int e = 0; e < 4; ++e) lacc[i][e] = 0.f;

    const int arow = tid >> 2, kq = tid & 3;
    const int asig = arow & 7;
    const int nloc = (wid << 6) + lane;
    const int sgl  = lane & 7;

    for (int p = 0; p < NPASS; ++p) {
        f32x16 acc[2][4];
        #pragma unroll
        for (int mf = 0; mf < 2; ++mf)
            #pragma unroll
            for (int nf = 0; nf < 4; ++nf)
                #pragma unroll
                for (int q = 0; q < 16; ++q) acc[mf][nf][q] = 0.f;

        for (int s = 0; s < 64; ++s) {
            __syncthreads();
            {
                const float* wp = W1 + (size_t)(s * 32) * DH + p * BN + nloc;
                short* rb = bs + nloc * 64;
                #pragma unroll
                for (int h = 0; h < 2; ++h) {
                    float f[16];
                    #pragma unroll
                    for (int j = 0; j < 16; ++j)
                        f[j] = wp[(size_t)(h * 16 + j) * DH];
                    uint32_t hd[8], ld_[8];
                    #pragma unroll
                    for (int q = 0; q < 8; ++q) {
                        uint32_t u0 = __float_as_uint(f[2 * q]);
                        uint32_t u1 = __float_as_uint(f[2 * q + 1]);
                        hd[q] = (u0 >> 16) | (u1 & 0xFFFF0000u);
                        float r0 = f[2 * q]     - __uint_as_float(u0 & 0xFFFF0000u);
                        float r1 = f[2 * q + 1] - __uint_as_float(u1 & 0xFFFF0000u);
                        ld_[q] = (__float_as_uint(r0) >> 16) | (__float_as_uint(r1) & 0xFFFF0000u);
                    }
                    *(int4*)(rb + (((2 * h + 0) ^ sgl) << 3)) = make_int4(hd[0], hd[1], hd[2], hd[3]);
                    *(int4*)(rb + (((2 * h + 1) ^ sgl) << 3)) = make_int4(hd[4], hd[5], hd[6], hd[7]);
                    *(int4*)(rb + (((4 + 2 * h + 0) ^ sgl) << 3)) = make_int4(ld_[0], ld_[1], ld_[2], ld_[3]);
                    *(int4*)(rb + (((4 + 2 * h + 1) ^ sgl) << 3)) = make_int4(ld_[4], ld_[5], ld_[6], ld_[7]);
                }
            }
            {
                const float* xp = x + (size_t)(m0 + arow) * DM + s * 32 + kq * 8;
                float4 v0 = *(const float4*)xp;
                float4 v1 = *(const float4*)(xp + 4);
                float f[8] = {v0.x, v0.y, v0.z, v0.w, v1.x, v1.y, v1.z, v1.w};
                uint32_t hd[4], ld_[4];
                #pragma unroll
                for (int q = 0; q < 4; ++q) {
                    uint32_t u0 = __float_as_uint(f[2 * q]);
                    uint32_t u1 = __float_as_uint(f[2 * q + 1]);
                    hd[q] = (u0 >> 16) | (u1 & 0xFFFF0000u);
                    float r0 = f[2 * q]     - __uint_as_float(u0 & 0xFFFF0000u);
                    float r1 = f[2 * q + 1] - __uint_as_float(u1 & 0xFFFF0000u);
                    ld_[q] = (__float_as_uint(r0) >> 16) | (__float_as_uint(r1) & 0xFFFF0000u);
                }
                short* ra = xs + arow * 64;
                *(int4*)(ra + ((kq ^ asig) << 3))       = make_int4(hd[0], hd[1], hd[2], hd[3]);
                *(int4*)(ra + (((4 + kq) ^ asig) << 3)) = make_int4(ld_[0], ld_[1], ld_[2], ld_[3]);
            }
            __syncthreads();
            #pragma unroll
            for (int ks = 0; ks < 2; ++ks) {
                bf16x8 a0[2], a1[2], b0[4], b1f[4];
                #pragma unroll
                for (int mf = 0; mf < 2; ++mf) {
                    int base = (wm * 64 + mf * 32 + l31) * 64;
                    a0[mf] = *(const bf16x8*)(xs + base + (((ks * 2 + lh)) ^ sg) * 8);
                    a1[mf] = *(const bf16x8*)(xs + base + (((4 + ks * 2 + lh)) ^ sg) * 8);
                }
                #pragma unroll
                for (int nf = 0; nf < 4; ++nf) {
                    int base = (wn * 128 + nf * 32 + l31) * 64;
                    b0[nf]  = *(const bf16x8*)(bs + base + (((ks * 2 + lh)) ^ sg) * 8);
                    b1f[nf] = *(const bf16x8*)(bs + base + (((4 + ks * 2 + lh)) ^ sg) * 8);
                }
                #pragma unroll
                for (int mf = 0; mf < 2; ++mf)
                    #pragma unroll
                    for (int nf = 0; nf < 4; ++nf) {
                        acc[mf][nf] = __builtin_amdgcn_mfma_f32_32x32x16_bf16(a0[mf], b0[nf],  acc[mf][nf], 0, 0, 0);
                        acc[mf][nf] = __builtin_amdgcn_mfma_f32_32x32x16_bf16(a0[mf], b1f[nf], acc[mf][nf], 0, 0, 0);
                        acc[mf][nf] = __builtin_amdgcn_mfma_f32_32x32x16_bf16(a1[mf], b0[nf],  acc[mf][nf], 0, 0, 0);
                    }
            }
        }

        for (int ch = 0; ch < 4; ++ch) {
            __syncthreads();
            if (wn == ch) {
                #pragma unroll
                for (int nf = 0; nf < 4; ++nf) {
                    int col = nf * 32 + l31;
                    float bb = b1[p * BN + ch * 128 + col];
                    #pragma unroll
                    for (int mf = 0; mf < 2; ++mf)
                        #pragma unroll
                        for (int r = 0; r < 16; ++r) {
                            int row = wm * 64 + mf * 32 + (r & 3) + 8 * (r >> 2) + 4 * lh;
                            h_lds[row * 128 + col] = fmaxf(acc[mf][nf][r] + bb, 0.f);
                        }
                }
            }
            #pragma unroll
            for (int q = 0; q < 4; ++q) {
                int i = tid * 4 + q;
                int nn = i >> 4, e = i & 15;
                w2t[e * 128 + nn] = W2[(size_t)(p * BN + ch * 128 + nn) * NE + e];
            }
            __syncthreads();
            for (int nn = 0; nn < 32; ++nn) {
                int nL = ns * 32 + ((nn + tq) & 31);
                float hv[4], wv[4];
                #pragma unroll
                for (int i = 0; i < 4; ++i) hv[i] = h_lds[(tq * 4 + i) * 128 + nL];
                #pragma unroll
                for (int e = 0; e < 4; ++e) wv[e] = w2t[(egq * 4 + e) * 128 + nL];
                #pragma unroll
                for (int i = 0; i < 4; ++i)
                    #pragma unroll
                    for (int e = 0; e < 4; ++e)
                        lacc[i][e] = fmaf(hv[i], wv[e], lacc[i][e]);
            }
        }
    }

    __syncthreads();
    #pragma unroll
    for (int i = 0; i < 4; ++i)
        #pragma unroll
        for (int e = 0; e < 4; ++e)
            lsred[((tq * 4 + i) * 16 + egq * 4 + e) * 4 + ns] = lacc[i][e];
    __syncthreads();
    #pragma unroll
    for (int q = 0; q < 4; ++q) {
        int idx = tid * 4 + q;
        int t = idx >> 4, e = idx & 15;
        ls[t * 17 + e] = lsred[idx * 4 + 0] + lsred[idx * 4 + 1] +
                         lsred[idx * 4 + 2] + lsred[idx * 4 + 3] + b2[e];
    }
    __syncthreads();

    if (tid < 128) {
        int t = tid;
        float l[NE]; float mx = -1e30f;
        #pragma unroll
        for (int e = 0; e < NE; ++e) { l[e] = ls[t * 17 + e]; mx = fmaxf(mx, l[e]); }
        float pb[NE]; float ssum = 0.f;
        #pragma unroll
        for (int e = 0; e < NE; ++e) { pb[e] = expf(l[e] - mx); ssum += pb[e]; }
        float inv = 1.f / ssum;
        #pragma unroll
        for (int e = 0; e < NE; ++e) pb[e] *= inv;

        int i1 = 0; float p1 = pb[0];
        #pragma unroll
        for (int e = 1; e < NE; ++e) if (pb[e] > p1) { p1 = pb[e]; i1 = e; }
        int i2 = -1; float p2 = -1.f;
        #pragma unroll
        for (int e = 0; e < NE; ++e) if (e != i1 && pb[e] > p2) { p2 = pb[e]; i2 = e; }
        float p3 = -1.f;
        #pragma unroll
        for (int e = 0; e < NE; ++e) if (e != i1 && e != i2 && pb[e] > p3) p3 = pb[e];

        float denom = p1 + p2 + 1e-8f;
        size_t gt = (size_t)(m0 + t);
        out[gt * 2 + 0] = p1 / denom;
        out[gt * 2 + 1] = p2 / denom;
        out[OFF_IDX + gt * 2 + 0] = (float)i1;
        out[OFF_IDX + gt * 2 + 1] = (float)i2;
        #pragma unroll
        for (int e = 0; e < NE; ++e) out[OFF_PROB + gt * 16 + e] = pb[e];

        if (p1 - p2 < FB_TAU || p2 - p3 < FB_TAU) {
            int k = atomicAdd(cnt, 1);
            list[k] = m0 + t;
        }
    }
}

extern "C" void kernel_launch(void* const* d_in, const int* in_sizes, int n_in,
                              void* d_out, int out_size, void* d_ws, size_t ws_size,
                              hipStream_t stream) {
    const float* x  = (const float*)d_in[0];
    const float* W1 = (const float*)d_in[1];
    const float* b1 = (const float*)d_in[2];
    const float* W2 = (const float*)d_in[3];
    const float* b2 = (const float*)d_in[4];
    float* out = (float*)d_out;

    int*   cnt   = (int*)d_ws;
    int*   list  = (int*)((char*)d_ws + WS_LIST);
    char*  wimg  = (char*)d_ws + WS_WT;
    float* hpart = (float*)wimg;   // repair partials alias wimg (used after router)

    hipMemsetAsync(cnt, 0, sizeof(int), stream);
    if (ws_size >= WS_NEEDED) {
        hipLaunchKernelGGL(prep_w16, dim3(NSTAGE * NPASS), dim3(256), 0, stream, W1, wimg);
        hipLaunchKernelGGL(router16, dim3(TOKENS / BM), dim3(512), 0, stream,
                           x, wimg, b1, W2, b2, out, cnt, list);
        hipLaunchKernelGGL(repair_partial, dim3(512), dim3(256), 0, stream,
                           x, W1, cnt, list, hpart);
        hipLaunchKernelGGL(repair_final, dim3(128), dim3(256), 0, stream,
                           hpart, b1, W2, b2, out, cnt, list);
        hipLaunchKernelGGL(repair4, dim3(128), dim3(256), 0, stream,
                           x, W1, b1, W2, b2, out, cnt, list, RCAP / 4);
    } else {
        hipLaunchKernelGGL(router_fb, dim3(TOKENS / 128), dim3(512), 0, stream,
                           x, W1, b1, W2, b2, out, cnt, list);
        hipLaunchKernelGGL(repair4, dim3(512), dim3(256), 0, stream,
                           x, W1, b1, W2, b2, out, cnt, list, 0);
    }
}